// Round 1
// baseline (25102.551 us; speedup 1.0000x reference)
//
#include <hip/hip_runtime.h>

#define T_STEPS 512
#define BATCH   64
#define HID     1024
#define GDIM    4096   // 4*H gate columns
#define KDIM    2048   // [h | x] fused K
#define LDA     40     // LDS row stride in bf16 elems (padded from 32)

using short8  = __attribute__((ext_vector_type(8))) short;
using floatx4 = __attribute__((ext_vector_type(4))) float;

__device__ inline unsigned short bf16_rne(float f) {
  union { float f; unsigned u; } x; x.f = f;
  unsigned r = x.u + 0x7FFFu + ((x.u >> 16) & 1u);
  return (unsigned short)(r >> 16);
}

__device__ inline float sigmoid_(float x) { return 1.0f / (1.0f + __expf(-x)); }
__device__ inline float tanh_(float x) {
  float e = __expf(-2.0f * fabsf(x));
  float r = (1.0f - e) / (1.0f + e);
  return copysignf(r, x);
}

#define LOAD4(dst, ptr) { float4 _t4 = *(const float4*)(ptr); \
  dst[0]=_t4.x; dst[1]=_t4.y; dst[2]=_t4.z; dst[3]=_t4.w; }

// ---------------------------------------------------------------------------
// One-time per call: pack [W_hh | W_ih] into bf16 Wcat[4096][2048]
// ---------------------------------------------------------------------------
__global__ __launch_bounds__(256) void cvt_w_kernel(
    const float* __restrict__ w_hh, const float* __restrict__ w_ih,
    unsigned short* __restrict__ wcat)
{
  int idx  = blockIdx.x * 256 + threadIdx.x;   // one thread per 4 elems
  int base = idx * 4;
  int g = base >> 11;        // /2048
  int k = base & 2047;
  const float* src = (k < 1024) ? (w_hh + (size_t)g * 1024 + k)
                                : (w_ih + (size_t)g * 1024 + (k - 1024));
  float a = src[0], b = src[1], c = src[2], d = src[3];
  uint2 v;
  v.x = (unsigned)bf16_rne(a) | ((unsigned)bf16_rne(b) << 16);
  v.y = (unsigned)bf16_rne(c) | ((unsigned)bf16_rne(d) << 16);
  *(uint2*)(wcat + base) = v;
}

// ---------------------------------------------------------------------------
// Per step: gates[64][4096] = [h | x_t] @ Wcat^T   (bf16 MFMA, fp32 acc)
// grid = 64 wgs (one 64-wide N tile each), block = 256 (4 waves)
// wave w computes m-rows [16w,16w+16), all 64 n-cols of the tile (4 frags)
// ---------------------------------------------------------------------------
__global__ __launch_bounds__(256) void gates_kernel(
    const float* __restrict__ hprev, const float* __restrict__ xt,
    const unsigned short* __restrict__ wcat, float* __restrict__ gates)
{
  __shared__ __align__(16) unsigned short As[64 * LDA];
  __shared__ __align__(16) unsigned short Bs[64 * LDA];
  const int tid  = threadIdx.x;
  const int n0   = blockIdx.x * 64;
  const int wave = tid >> 6;
  const int lane = tid & 63;
  const int quad = lane >> 4;
  const int l16  = lane & 15;
  const int srow = tid >> 2;         // staging: row 0..63
  const int scol = (tid & 3) * 8;    // staging: col 0,8,16,24

  floatx4 acc[4] = {{0,0,0,0},{0,0,0,0},{0,0,0,0},{0,0,0,0}};

  for (int k0 = 0; k0 < KDIM; k0 += 32) {
    // global loads for this K-chunk (fp32 A with on-the-fly bf16 convert)
    const float* ap = (k0 < 1024)
        ? (hprev + (size_t)srow * 1024 + k0 + scol)
        : (xt    + (size_t)srow * 1024 + (k0 - 1024) + scol);
    float4 a0 = *(const float4*)ap;
    float4 a1 = *(const float4*)(ap + 4);
    uint4 av;
    av.x = (unsigned)bf16_rne(a0.x) | ((unsigned)bf16_rne(a0.y) << 16);
    av.y = (unsigned)bf16_rne(a0.z) | ((unsigned)bf16_rne(a0.w) << 16);
    av.z = (unsigned)bf16_rne(a1.x) | ((unsigned)bf16_rne(a1.y) << 16);
    av.w = (unsigned)bf16_rne(a1.z) | ((unsigned)bf16_rne(a1.w) << 16);
    uint4 bv = *(const uint4*)(wcat + (size_t)(n0 + srow) * KDIM + k0 + scol);

    __syncthreads();   // previous iter's frag reads done before overwrite
    *(uint4*)(&As[srow * LDA + scol]) = av;
    *(uint4*)(&Bs[srow * LDA + scol]) = bv;
    __syncthreads();

    // A-frag: A[m=lane&15][k=quad*8+j]; B-frag same from B^T (N,K) layout
    short8 af = *(const short8*)(&As[(wave * 16 + l16) * LDA + quad * 8]);
#pragma unroll
    for (int nt = 0; nt < 4; ++nt) {
      short8 bf = *(const short8*)(&Bs[(nt * 16 + l16) * LDA + quad * 8]);
      acc[nt] = __builtin_amdgcn_mfma_f32_16x16x32_bf16(af, bf, acc[nt], 0, 0, 0);
    }
  }

  // C/D layout (m89-verified): col = lane&15, row = quad*4 + reg
#pragma unroll
  for (int nt = 0; nt < 4; ++nt) {
#pragma unroll
    for (int r = 0; r < 4; ++r) {
      int m = wave * 16 + quad * 4 + r;
      int n = n0 + nt * 16 + l16;
      gates[(size_t)m * GDIM + n] = acc[nt][r];
    }
  }
}

// ---------------------------------------------------------------------------
// block reduce: sum N accumulators across 256 threads (4 waves of 64)
// ---------------------------------------------------------------------------
template<int N>
__device__ inline void block_reduce(float* v, float* red, int tid) {
#pragma unroll
  for (int i = 0; i < N; ++i) {
    float x = v[i];
#pragma unroll
    for (int off = 32; off > 0; off >>= 1)
      x += __shfl_xor(x, off, 64);
    v[i] = x;
  }
  const int wave = tid >> 6;
  if ((tid & 63) == 0) {
#pragma unroll
    for (int i = 0; i < N; ++i) red[wave * N + i] = v[i];
  }
  __syncthreads();
#pragma unroll
  for (int i = 0; i < N; ++i)
    v[i] = red[i] + red[N + i] + red[2 * N + i] + red[3 * N + i];
}

// ---------------------------------------------------------------------------
// Per step: LN + gate pointwise for one batch row per wg; writes h_t, updates c
// ---------------------------------------------------------------------------
__global__ __launch_bounds__(256) void step_kernel(
    const float* __restrict__ gates, float* __restrict__ c_ws,
    const float* __restrict__ w_ch, const float* __restrict__ bias,
    const float* __restrict__ gamma_f, const float* __restrict__ gamma_i,
    const float* __restrict__ gamma_g, const float* __restrict__ gamma_o,
    const float* __restrict__ gamma_c, const float* __restrict__ beta_c,
    float* __restrict__ hout)
{
  __shared__ float sm[40];
  const int b   = blockIdx.x;
  const int tid = threadIdx.x;
  const int j   = tid * 4;
  const float* grow = gates + (size_t)b * GDIM;

  float fh[4], ih[4], gh[4], oh[4], cc[4], wcf[4], wci[4], wco[4];
  LOAD4(fh, grow + j);
  LOAD4(ih, grow + HID + j);
  LOAD4(gh, grow + 2 * HID + j);
  LOAD4(oh, grow + 3 * HID + j);
  LOAD4(cc, c_ws + (size_t)b * HID + j);
  LOAD4(wcf, w_ch + j);
  LOAD4(wci, w_ch + HID + j);
  LOAD4(wco, w_ch + 2 * HID + j);

  float af[4], ai[4], ag[4];
  float s[6] = {0, 0, 0, 0, 0, 0};
#pragma unroll
  for (int r = 0; r < 4; ++r) {
    af[r] = fh[r] + wcf[r] * cc[r];
    ai[r] = ih[r] + wci[r] * cc[r];
    ag[r] = gh[r];
    s[0] += af[r]; s[1] += af[r] * af[r];
    s[2] += ai[r]; s[3] += ai[r] * ai[r];
    s[4] += ag[r]; s[5] += ag[r] * ag[r];
  }
  block_reduce<6>(s, sm, tid);
  const float invH = 1.0f / (float)HID;
  float mu_f = s[0] * invH, is_f = rsqrtf(s[1] * invH - mu_f * mu_f + 1e-5f);
  float mu_i = s[2] * invH, is_i = rsqrtf(s[3] * invH - mu_i * mu_i + 1e-5f);
  float mu_g = s[4] * invH, is_g = rsqrtf(s[5] * invH - mu_g * mu_g + 1e-5f);

  float gf4[4], gi4[4], gg4[4], bf4[4], bi4[4], bg4[4];
  LOAD4(gf4, gamma_f + j); LOAD4(gi4, gamma_i + j); LOAD4(gg4, gamma_g + j);
  LOAD4(bf4, bias + j);    LOAD4(bi4, bias + HID + j); LOAD4(bg4, bias + 2 * HID + j);

  float cn[4], ao[4];
  float s2[4] = {0, 0, 0, 0};
#pragma unroll
  for (int r = 0; r < 4; ++r) {
    float f = sigmoid_((af[r] - mu_f) * is_f * gf4[r] + bf4[r]);
    float i = sigmoid_((ai[r] - mu_i) * is_i * gi4[r] + bi4[r]);
    float g = tanh_((ag[r] - mu_g) * is_g * gg4[r] + bg4[r]);
    cn[r] = f * cc[r] + i * g;
    ao[r] = oh[r] + wco[r] * cn[r];
    s2[0] += cn[r]; s2[1] += cn[r] * cn[r];
    s2[2] += ao[r]; s2[3] += ao[r] * ao[r];
  }
  { float4 t; t.x = cn[0]; t.y = cn[1]; t.z = cn[2]; t.w = cn[3];
    *(float4*)(c_ws + (size_t)b * HID + j) = t; }

  block_reduce<4>(s2, sm + 24, tid);
  float mu_c = s2[0] * invH, is_c = rsqrtf(s2[1] * invH - mu_c * mu_c + 1e-5f);
  float mu_o = s2[2] * invH, is_o = rsqrtf(s2[3] * invH - mu_o * mu_o + 1e-5f);

  float gc4[4], bc4[4], go4[4], bo4[4];
  LOAD4(gc4, gamma_c + j); LOAD4(bc4, beta_c + j);
  LOAD4(go4, gamma_o + j); LOAD4(bo4, bias + 3 * HID + j);

  float h4[4];
#pragma unroll
  for (int r = 0; r < 4; ++r) {
    float cl = (cn[r] - mu_c) * is_c * gc4[r] + bc4[r];
    float o  = sigmoid_((ao[r] - mu_o) * is_o * go4[r] + bo4[r]);
    h4[r] = o * tanh_(cl);
  }
  { float4 t; t.x = h4[0]; t.y = h4[1]; t.z = h4[2]; t.w = h4[3];
    *(float4*)(hout + (size_t)b * HID + j) = t; }
}

// ---------------------------------------------------------------------------
extern "C" void kernel_launch(void* const* d_in, const int* in_sizes, int n_in,
                              void* d_out, int out_size, void* d_ws, size_t ws_size,
                              hipStream_t stream) {
  (void)in_sizes; (void)n_in; (void)out_size; (void)ws_size;
  const float* input   = (const float*)d_in[0];
  const float* hidden  = (const float*)d_in[1];
  const float* cell    = (const float*)d_in[2];
  const float* w_ih    = (const float*)d_in[3];
  const float* w_hh    = (const float*)d_in[4];
  const float* w_ch    = (const float*)d_in[5];
  const float* bias    = (const float*)d_in[6];
  const float* gamma_f = (const float*)d_in[7];
  const float* gamma_i = (const float*)d_in[8];
  const float* gamma_g = (const float*)d_in[9];
  const float* gamma_o = (const float*)d_in[10];
  const float* gamma_c = (const float*)d_in[11];
  const float* beta_c  = (const float*)d_in[12];
  float* out = (float*)d_out;

  // workspace layout: [ Wcat bf16 16 MB | c 256 KB | gates 1 MB ]
  unsigned short* wcat = (unsigned short*)d_ws;
  float* c_ws  = (float*)((char*)d_ws + (size_t)GDIM * KDIM * sizeof(unsigned short));
  float* gates = c_ws + BATCH * HID;

  cvt_w_kernel<<<(GDIM * KDIM / 4) / 256, 256, 0, stream>>>(w_hh, w_ih, wcat);
  hipMemcpyAsync(c_ws, cell, (size_t)BATCH * HID * sizeof(float),
                 hipMemcpyDeviceToDevice, stream);

  for (int t = 0; t < T_STEPS; ++t) {
    const float* hprev = (t == 0) ? hidden : (out + (size_t)(t - 1) * BATCH * HID);
    gates_kernel<<<64, 256, 0, stream>>>(
        hprev, input + (size_t)t * BATCH * HID, wcat, gates);
    step_kernel<<<64, 256, 0, stream>>>(
        gates, c_ws, w_ch, bias, gamma_f, gamma_i, gamma_g, gamma_o,
        gamma_c, beta_c, out + (size_t)t * BATCH * HID);
  }

  const size_t OUT0 = (size_t)T_STEPS * BATCH * HID;
  hipMemcpyAsync(out + OUT0, out + (OUT0 - BATCH * HID),
                 (size_t)BATCH * HID * sizeof(float), hipMemcpyDeviceToDevice, stream);
  hipMemcpyAsync(out + OUT0 + BATCH * HID, c_ws,
                 (size_t)BATCH * HID * sizeof(float), hipMemcpyDeviceToDevice, stream);
}

// Round 2
// 11573.026 us; speedup vs baseline: 2.1691x; 2.1691x over previous
//
#include <hip/hip_runtime.h>

#define T_STEPS 512
#define BATCH   64
#define HID     1024
#define GDIM    4096   // 4*H gate columns
#define KDIM    2048   // [h | x] fused K

using short8  = __attribute__((ext_vector_type(8))) short;
using floatx4 = __attribute__((ext_vector_type(4))) float;

__device__ inline unsigned short bf16_rne(float f) {
  union { float f; unsigned u; } x; x.f = f;
  unsigned r = x.u + 0x7FFFu + ((x.u >> 16) & 1u);
  return (unsigned short)(r >> 16);
}

__device__ inline float sigmoid_(float x) { return 1.0f / (1.0f + __expf(-x)); }
__device__ inline float tanh_(float x) {
  float e = __expf(-2.0f * fabsf(x));
  float r = (1.0f - e) / (1.0f + e);
  return copysignf(r, x);
}

#define LOAD4(dst, ptr) { float4 _t4 = *(const float4*)(ptr); \
  dst[0]=_t4.x; dst[1]=_t4.y; dst[2]=_t4.z; dst[3]=_t4.w; }

// ---------------------------------------------------------------------------
// One-time per call: pack [W_hh | W_ih] into bf16 Wcat[4096][2048]
// ---------------------------------------------------------------------------
__global__ __launch_bounds__(256) void cvt_w_kernel(
    const float* __restrict__ w_hh, const float* __restrict__ w_ih,
    unsigned short* __restrict__ wcat)
{
  int idx  = blockIdx.x * 256 + threadIdx.x;   // one thread per 4 elems
  int base = idx * 4;
  int g = base >> 11;        // /2048
  int k = base & 2047;
  const float* src = (k < 1024) ? (w_hh + (size_t)g * 1024 + k)
                                : (w_ih + (size_t)g * 1024 + (k - 1024));
  float a = src[0], b = src[1], c = src[2], d = src[3];
  uint2 v;
  v.x = (unsigned)bf16_rne(a) | ((unsigned)bf16_rne(b) << 16);
  v.y = (unsigned)bf16_rne(c) | ((unsigned)bf16_rne(d) << 16);
  *(uint2*)(wcat + base) = v;
}

// ---------------------------------------------------------------------------
// One-time per call: h0, x0 -> bf16 side buffers; cell -> c_ws
// grid = 64 (one wg per batch row), block = 256
// ---------------------------------------------------------------------------
__global__ __launch_bounds__(256) void init_kernel(
    const float* __restrict__ hidden, const float* __restrict__ x0,
    const float* __restrict__ cell,
    unsigned short* __restrict__ hbf, unsigned short* __restrict__ xbf,
    float* __restrict__ c_ws)
{
  const int b = blockIdx.x;
  const int j = threadIdx.x * 4;
  const size_t off = (size_t)b * HID + j;
  float4 h = *(const float4*)(hidden + off);
  float4 x = *(const float4*)(x0 + off);
  float4 c = *(const float4*)(cell + off);
  ushort4 hv, xv;
  hv.x = bf16_rne(h.x); hv.y = bf16_rne(h.y); hv.z = bf16_rne(h.z); hv.w = bf16_rne(h.w);
  xv.x = bf16_rne(x.x); xv.y = bf16_rne(x.y); xv.z = bf16_rne(x.z); xv.w = bf16_rne(x.w);
  *(ushort4*)(hbf + off) = hv;
  *(ushort4*)(xbf + off) = xv;
  *(float4*)(c_ws + off) = c;
}

// ---------------------------------------------------------------------------
// Per step: gates[64][4096] = [h | x_t](bf16) @ Wcat^T   (MFMA, fp32 acc)
// grid = 256 wgs (one 16-col N tile each, full K), block = 256 (4 waves)
// wave w: rows [16w,16w+16) x 16 cols. NO LDS, NO barriers — fragments are
// loaded straight from global (A: 16 rows x 128B contig; B: L2-resident).
// Two acc chains break the dependent-MFMA latency chain.
// ---------------------------------------------------------------------------
__global__ __launch_bounds__(256) void gates_kernel(
    const unsigned short* __restrict__ hbf,
    const unsigned short* __restrict__ xbf,
    const unsigned short* __restrict__ wcat,
    float* __restrict__ gates)
{
  const int tid  = threadIdx.x;
  const int wave = tid >> 6;
  const int lane = tid & 63;
  const int quad = lane >> 4;
  const int l16  = lane & 15;
  const int n    = blockIdx.x * 16 + l16;     // output column (= Wcat row)

  // A-frag: A[m = lane&15][k = quad*8 + j]  (m89-verified 16x16x32 layout)
  // B-frag: B[k][n] = Wcat[n][k] -> same quad*8 k-offset, row n
  const unsigned short* brow = wcat + (size_t)n * KDIM + quad * 8;
  const unsigned short* arow = hbf + (size_t)(wave * 16 + l16) * HID + quad * 8;
  const unsigned short* xrow = xbf + (size_t)(wave * 16 + l16) * HID + quad * 8;

  floatx4 acc0 = {0, 0, 0, 0}, acc1 = {0, 0, 0, 0};

  // K = 0..1024: h part
#pragma unroll 8
  for (int kc = 0; kc < 32; kc += 2) {
    short8 b0 = *(const short8*)(brow + kc * 32);
    short8 a0 = *(const short8*)(arow + kc * 32);
    short8 b1 = *(const short8*)(brow + kc * 32 + 32);
    short8 a1 = *(const short8*)(arow + kc * 32 + 32);
    acc0 = __builtin_amdgcn_mfma_f32_16x16x32_bf16(a0, b0, acc0, 0, 0, 0);
    acc1 = __builtin_amdgcn_mfma_f32_16x16x32_bf16(a1, b1, acc1, 0, 0, 0);
  }
  // K = 1024..2048: x part
#pragma unroll 8
  for (int kc = 0; kc < 32; kc += 2) {
    short8 b0 = *(const short8*)(brow + 1024 + kc * 32);
    short8 a0 = *(const short8*)(xrow + kc * 32);
    short8 b1 = *(const short8*)(brow + 1024 + kc * 32 + 32);
    short8 a1 = *(const short8*)(xrow + kc * 32 + 32);
    acc0 = __builtin_amdgcn_mfma_f32_16x16x32_bf16(a0, b0, acc0, 0, 0, 0);
    acc1 = __builtin_amdgcn_mfma_f32_16x16x32_bf16(a1, b1, acc1, 0, 0, 0);
  }

  // C/D layout (m89-verified): col = lane&15, row = quad*4 + reg
#pragma unroll
  for (int r = 0; r < 4; ++r) {
    int m = wave * 16 + quad * 4 + r;
    gates[(size_t)m * GDIM + n] = acc0[r] + acc1[r];
  }
}

// ---------------------------------------------------------------------------
// block reduce: sum N accumulators across 256 threads (4 waves of 64)
// ---------------------------------------------------------------------------
template<int N>
__device__ inline void block_reduce(float* v, float* red, int tid) {
#pragma unroll
  for (int i = 0; i < N; ++i) {
    float x = v[i];
#pragma unroll
    for (int off = 32; off > 0; off >>= 1)
      x += __shfl_xor(x, off, 64);
    v[i] = x;
  }
  const int wave = tid >> 6;
  if ((tid & 63) == 0) {
#pragma unroll
    for (int i = 0; i < N; ++i) red[wave * N + i] = v[i];
  }
  __syncthreads();
#pragma unroll
  for (int i = 0; i < N; ++i)
    v[i] = red[i] + red[N + i] + red[2 * N + i] + red[3 * N + i];
}

// ---------------------------------------------------------------------------
// Per step: LN + gate pointwise for one batch row per wg; writes h_t (fp32 to
// out, bf16 to hbf), updates c, converts x_{t+1} -> xbf for the next step.
// ---------------------------------------------------------------------------
__global__ __launch_bounds__(256) void step_kernel(
    const float* __restrict__ gates, float* __restrict__ c_ws,
    const float* __restrict__ w_ch, const float* __restrict__ bias,
    const float* __restrict__ gamma_f, const float* __restrict__ gamma_i,
    const float* __restrict__ gamma_g, const float* __restrict__ gamma_o,
    const float* __restrict__ gamma_c, const float* __restrict__ beta_c,
    float* __restrict__ hout, unsigned short* __restrict__ hbf,
    const float* __restrict__ xnext, unsigned short* __restrict__ xbf,
    int has_next)
{
  __shared__ float sm[40];
  const int b   = blockIdx.x;
  const int tid = threadIdx.x;
  const int j   = tid * 4;
  const float* grow = gates + (size_t)b * GDIM;

  float fh[4], ih[4], gh[4], oh[4], cc[4], wcf[4], wci[4], wco[4];
  LOAD4(fh, grow + j);
  LOAD4(ih, grow + HID + j);
  LOAD4(gh, grow + 2 * HID + j);
  LOAD4(oh, grow + 3 * HID + j);
  LOAD4(cc, c_ws + (size_t)b * HID + j);
  LOAD4(wcf, w_ch + j);
  LOAD4(wci, w_ch + HID + j);
  LOAD4(wco, w_ch + 2 * HID + j);

  float af[4], ai[4], ag[4];
  float s[6] = {0, 0, 0, 0, 0, 0};
#pragma unroll
  for (int r = 0; r < 4; ++r) {
    af[r] = fh[r] + wcf[r] * cc[r];
    ai[r] = ih[r] + wci[r] * cc[r];
    ag[r] = gh[r];
    s[0] += af[r]; s[1] += af[r] * af[r];
    s[2] += ai[r]; s[3] += ai[r] * ai[r];
    s[4] += ag[r]; s[5] += ag[r] * ag[r];
  }
  block_reduce<6>(s, sm, tid);
  const float invH = 1.0f / (float)HID;
  float mu_f = s[0] * invH, is_f = rsqrtf(s[1] * invH - mu_f * mu_f + 1e-5f);
  float mu_i = s[2] * invH, is_i = rsqrtf(s[3] * invH - mu_i * mu_i + 1e-5f);
  float mu_g = s[4] * invH, is_g = rsqrtf(s[5] * invH - mu_g * mu_g + 1e-5f);

  float gf4[4], gi4[4], gg4[4], bf4[4], bi4[4], bg4[4];
  LOAD4(gf4, gamma_f + j); LOAD4(gi4, gamma_i + j); LOAD4(gg4, gamma_g + j);
  LOAD4(bf4, bias + j);    LOAD4(bi4, bias + HID + j); LOAD4(bg4, bias + 2 * HID + j);

  float cn[4], ao[4];
  float s2[4] = {0, 0, 0, 0};
#pragma unroll
  for (int r = 0; r < 4; ++r) {
    float f = sigmoid_((af[r] - mu_f) * is_f * gf4[r] + bf4[r]);
    float i = sigmoid_((ai[r] - mu_i) * is_i * gi4[r] + bi4[r]);
    float g = tanh_((ag[r] - mu_g) * is_g * gg4[r] + bg4[r]);
    cn[r] = f * cc[r] + i * g;
    ao[r] = oh[r] + wco[r] * cn[r];
    s2[0] += cn[r]; s2[1] += cn[r] * cn[r];
    s2[2] += ao[r]; s2[3] += ao[r] * ao[r];
  }
  { float4 t; t.x = cn[0]; t.y = cn[1]; t.z = cn[2]; t.w = cn[3];
    *(float4*)(c_ws + (size_t)b * HID + j) = t; }

  block_reduce<4>(s2, sm + 24, tid);
  float mu_c = s2[0] * invH, is_c = rsqrtf(s2[1] * invH - mu_c * mu_c + 1e-5f);
  float mu_o = s2[2] * invH, is_o = rsqrtf(s2[3] * invH - mu_o * mu_o + 1e-5f);

  float gc4[4], bc4[4], go4[4], bo4[4];
  LOAD4(gc4, gamma_c + j); LOAD4(bc4, beta_c + j);
  LOAD4(go4, gamma_o + j); LOAD4(bo4, bias + 3 * HID + j);

  float h4[4];
#pragma unroll
  for (int r = 0; r < 4; ++r) {
    float cl = (cn[r] - mu_c) * is_c * gc4[r] + bc4[r];
    float o  = sigmoid_((ao[r] - mu_o) * is_o * go4[r] + bo4[r]);
    h4[r] = o * tanh_(cl);
  }
  { float4 t; t.x = h4[0]; t.y = h4[1]; t.z = h4[2]; t.w = h4[3];
    *(float4*)(hout + (size_t)b * HID + j) = t; }
  { ushort4 hv;
    hv.x = bf16_rne(h4[0]); hv.y = bf16_rne(h4[1]);
    hv.z = bf16_rne(h4[2]); hv.w = bf16_rne(h4[3]);
    *(ushort4*)(hbf + (size_t)b * HID + j) = hv; }

  if (has_next) {
    float4 xv = *(const float4*)(xnext + (size_t)b * HID + j);
    ushort4 xb;
    xb.x = bf16_rne(xv.x); xb.y = bf16_rne(xv.y);
    xb.z = bf16_rne(xv.z); xb.w = bf16_rne(xv.w);
    *(ushort4*)(xbf + (size_t)b * HID + j) = xb;
  }
}

// ---------------------------------------------------------------------------
extern "C" void kernel_launch(void* const* d_in, const int* in_sizes, int n_in,
                              void* d_out, int out_size, void* d_ws, size_t ws_size,
                              hipStream_t stream) {
  (void)in_sizes; (void)n_in; (void)out_size; (void)ws_size;
  const float* input   = (const float*)d_in[0];
  const float* hidden  = (const float*)d_in[1];
  const float* cell    = (const float*)d_in[2];
  const float* w_ih    = (const float*)d_in[3];
  const float* w_hh    = (const float*)d_in[4];
  const float* w_ch    = (const float*)d_in[5];
  const float* bias    = (const float*)d_in[6];
  const float* gamma_f = (const float*)d_in[7];
  const float* gamma_i = (const float*)d_in[8];
  const float* gamma_g = (const float*)d_in[9];
  const float* gamma_o = (const float*)d_in[10];
  const float* gamma_c = (const float*)d_in[11];
  const float* beta_c  = (const float*)d_in[12];
  float* out = (float*)d_out;

  // workspace: [ Wcat bf16 16MB | gates 1MB | c 256KB | hbf 128KB | xbf 128KB ]
  unsigned short* wcat = (unsigned short*)d_ws;
  float* gates = (float*)((char*)d_ws + (size_t)GDIM * KDIM * sizeof(unsigned short));
  float* c_ws  = gates + (size_t)BATCH * GDIM;
  unsigned short* hbf = (unsigned short*)(c_ws + BATCH * HID);
  unsigned short* xbf = hbf + BATCH * HID;

  cvt_w_kernel<<<(GDIM * KDIM / 4) / 256, 256, 0, stream>>>(w_hh, w_ih, wcat);
  init_kernel<<<BATCH, 256, 0, stream>>>(hidden, input, cell, hbf, xbf, c_ws);

  for (int t = 0; t < T_STEPS; ++t) {
    gates_kernel<<<256, 256, 0, stream>>>(hbf, xbf, wcat, gates);
    int has_next = (t + 1 < T_STEPS) ? 1 : 0;
    const float* xnext = input + (size_t)(has_next ? (t + 1) : t) * BATCH * HID;
    step_kernel<<<BATCH, 256, 0, stream>>>(
        gates, c_ws, w_ch, bias, gamma_f, gamma_i, gamma_g, gamma_o,
        gamma_c, beta_c, out + (size_t)t * BATCH * HID, hbf,
        xnext, xbf, has_next);
  }

  const size_t OUT0 = (size_t)T_STEPS * BATCH * HID;
  hipMemcpyAsync(out + OUT0, out + (OUT0 - BATCH * HID),
                 (size_t)BATCH * HID * sizeof(float), hipMemcpyDeviceToDevice, stream);
  hipMemcpyAsync(out + OUT0 + BATCH * HID, c_ws,
                 (size_t)BATCH * HID * sizeof(float), hipMemcpyDeviceToDevice, stream);
}